// Round 5
// baseline (614.793 us; speedup 1.0000x reference)
//
#include <hip/hip_runtime.h>

// LogicGatedSNN R5: x-as-bitmask + deep load batching.
//
// R4 post-mortem: three different structures all ~200 us at 2.6-2.75 TB/s
// while write-only fills hit 6.5 TB/s. Read path is the cap: 768 MB logical
// reads (syn 256 + trace 256 + x re-read 256 MB/launch) and VGPR=16 showed
// only ~2 loads in flight per wave (latency x outstanding bound).
// This version:
//   - x packed once into a 1 KB bitmask (x is exactly {0,1}); staged into
//     1 KB LDS per block. x read traffic: 256 MB -> ~2 MB.
//   - syn/trace loads explicitly batched 8-deep into registers.
//   - per-row scalars hoisted to kernel start.
// Exactness: current counts integer 1.0 adds (order-free, exact); trace
// update is 1-ulp FMA-level vs numpy (threshold 2e-2).

#define IN_F 8192
#define OUT_F 8192
#define BLOCK 256
#define BATCH 8
#define NBATCH (IN_F / 4 / 64 / BATCH)   // 32 iters / 8 = 4

typedef float vfloat4 __attribute__((ext_vector_type(4)));

// ---- Kernel 0: pack x into 8192-bit mask (256 u32 words) in d_ws ----
__global__ __launch_bounds__(BLOCK) void snn_pack_x(
    const float* __restrict__ x, unsigned long long* __restrict__ mask64)
{
    const int wave = threadIdx.x >> 6;
    const int lane = threadIdx.x & 63;
    #pragma unroll
    for (int s = 0; s < 32; ++s) {
        const float v = x[(wave << 11) + (s << 6) + lane];
        const unsigned long long b = __ballot(v != 0.0f);
        if (lane == 0) mask64[(wave << 5) + s] = b;
    }
}

// ---- Main kernel: wave-per-row, x from LDS bitmask ----
__global__ __launch_bounds__(BLOCK) void snn_main_kernel(
    const unsigned int* __restrict__ xbits,  // [256] u32 bitmask of x
    const float* __restrict__ syn,           // [OUT_F, IN_F]
    const float* __restrict__ mem,           // [OUT_F]
    const float* __restrict__ thr,           // [OUT_F]
    const float* __restrict__ trace,         // [OUT_F, IN_F]
    const float* __restrict__ refr,          // [OUT_F]
    float* __restrict__ out_spikes,
    float* __restrict__ out_mem,
    float* __restrict__ out_trace,
    float* __restrict__ out_refr)
{
    __shared__ unsigned int sbits[IN_F / 32];   // 1 KB
    const int wave = threadIdx.x >> 6;
    const int lane = threadIdx.x & 63;
    const int row  = (blockIdx.x << 2) + wave;

    // Early per-row scalar loads (in flight during phase 1).
    const float r  = refr[row];
    const float m0 = mem[row];
    const float th = thr[row];

    sbits[threadIdx.x] = xbits[threadIdx.x];
    __syncthreads();

    const vfloat4* __restrict__ syn4 =
        (const vfloat4*)(syn + (size_t)row * IN_F);
    const vfloat4* __restrict__ tr4 =
        (const vfloat4*)(trace + (size_t)row * IN_F);
    vfloat4* __restrict__ otr4 = (vfloat4*)(out_trace + (size_t)row * IN_F);

    // Phase 1: current = popcount-style gated sum. 8 loads in flight.
    float acc = 0.0f;
    #pragma unroll
    for (int ib = 0; ib < NBATCH; ++ib) {
        vfloat4 s[BATCH];
        #pragma unroll
        for (int b = 0; b < BATCH; ++b) {
            s[b] = syn4[(((ib << 3) + b) << 6) + lane];
        }
        #pragma unroll
        for (int b = 0; b < BATCH; ++b) {
            const int idx = (((ib << 3) + b) << 6) + lane;
            const unsigned int bits = sbits[idx >> 3] >> ((idx & 7) << 2);
            acc += ((s[b].x > 50.0f) && (bits & 1u)) ? 1.0f : 0.0f;
            acc += ((s[b].y > 50.0f) && (bits & 2u)) ? 1.0f : 0.0f;
            acc += ((s[b].z > 50.0f) && (bits & 4u)) ? 1.0f : 0.0f;
            acc += ((s[b].w > 50.0f) && (bits & 8u)) ? 1.0f : 0.0f;
        }
    }
    #pragma unroll
    for (int off = 32; off > 0; off >>= 1) {
        acc += __shfl_down(acc, off, 64);
    }
    const float current = __shfl(acc, 0, 64);

    // Phase 2: LIF scalars.
    const float v = m0 * 0.5f + current * (1.0f - r * 0.5f);
    const float spike = (v >= th) ? 1.0f : 0.0f;
    if (lane == 0) {
        out_spikes[row] = spike;
        out_mem[row]    = v * (1.0f - spike);
        out_refr[row]   = fminf(fmaxf(r + spike - 0.1f, 0.0f), 1.0f);
    }

    // Phase 3: trace stream, 8 loads in flight, x from bitmask.
    #pragma unroll
    for (int ib = 0; ib < NBATCH; ++ib) {
        vfloat4 t[BATCH];
        #pragma unroll
        for (int b = 0; b < BATCH; ++b) {
            t[b] = tr4[(((ib << 3) + b) << 6) + lane];
        }
        #pragma unroll
        for (int b = 0; b < BATCH; ++b) {
            const int idx = (((ib << 3) + b) << 6) + lane;
            const unsigned int bits = sbits[idx >> 3] >> ((idx & 7) << 2);
            vfloat4 o;
            o.x = fminf(fmaxf(t[b].x * 0.8f + ((bits & 1u) ? spike : 0.0f), 0.0f), 5.0f);
            o.y = fminf(fmaxf(t[b].y * 0.8f + ((bits & 2u) ? spike : 0.0f), 0.0f), 5.0f);
            o.z = fminf(fmaxf(t[b].z * 0.8f + ((bits & 4u) ? spike : 0.0f), 0.0f), 5.0f);
            o.w = fminf(fmaxf(t[b].w * 0.8f + ((bits & 8u) ? spike : 0.0f), 0.0f), 5.0f);
            __builtin_nontemporal_store(o, &otr4[idx]);
        }
    }
}

extern "C" void kernel_launch(void* const* d_in, const int* in_sizes, int n_in,
                              void* d_out, int out_size, void* d_ws, size_t ws_size,
                              hipStream_t stream) {
    const float* x_in  = (const float*)d_in[0];  // spike_input
    const float* syn   = (const float*)d_in[1];  // synapse_states
    const float* mem   = (const float*)d_in[2];  // membrane_potential
    const float* thr   = (const float*)d_in[3];  // adaptive_threshold
    const float* trace = (const float*)d_in[4];  // eligibility_trace
    const float* refr  = (const float*)d_in[5];  // refractory_period

    float* out = (float*)d_out;
    float* out_spikes = out;                                     // [8192]
    float* out_mem    = out + OUT_F;                             // [8192]
    float* out_trace  = out + 2 * OUT_F;                         // [8192^2]
    float* out_refr   = out + 2 * OUT_F + (size_t)OUT_F * IN_F;  // [8192]

    snn_pack_x<<<1, BLOCK, 0, stream>>>(
        x_in, (unsigned long long*)d_ws);

    snn_main_kernel<<<OUT_F / 4, BLOCK, 0, stream>>>(
        (const unsigned int*)d_ws, syn, mem, thr, trace, refr,
        out_spikes, out_mem, out_trace, out_refr);
}

// Round 6
// 602.309 us; speedup vs baseline: 1.0207x; 1.0207x over previous
//
#include <hip/hip_runtime.h>

// LogicGatedSNN R6: flat copy-shaped grid-stride streams.
//
// R5 post-mortem: five structures (block-row LDS / split / wave-row /
// 8-deep batch / bitmask-x) ALL land 196-209 us at ~2.6 TB/s, across
// occupancy 30-79% and VGPR 16-68. The only shared trait: each wave
// privately streams a 32 KB row -> ~8192 desynced DRAM streams 32 KB
// apart. The patterns that hit 6.3-6.5 TB/s here (harness fills, float4
// copy ubench) are flat grid-stride streams with one contiguous marching
// footprint. This version restructures all work into that shape:
//   A : flat stream over syn; per-wave 256-elem chunk is within one row;
//       shfl-reduce -> partial[chunk] in d_ws (1 MB, all slots written,
//       no atomics, integer-exact).
//   A2: 8192 threads: current[row] = sum of 32 partials; LIF scalars.
//   B : flat stream: out[i] = clip(tr[i]*0.8 + spike[i>>13]*x[i&8191]).

#define IN_F 8192
#define OUT_F 8192
#define BLOCK 256
#define GRID 2048
#define TOTAL4 (OUT_F * IN_F / 4)       // 16777216 float4 elements
#define STRIDE4 (GRID * BLOCK)          // 524288
#define ITERS (TOTAL4 / STRIDE4)        // 32

typedef float vfloat4 __attribute__((ext_vector_type(4)));

// ---- Kernel A: flat binarized-dot partials -------------------------------
__global__ __launch_bounds__(BLOCK) void snn_dot_flat(
    const vfloat4* __restrict__ syn4,   // [TOTAL4]
    const vfloat4* __restrict__ x4,     // [IN_F/4] = 2048
    float* __restrict__ partial)        // [TOTAL4/64] = 262144 (in d_ws)
{
    const int lane = threadIdx.x & 63;
    size_t g = (size_t)blockIdx.x * BLOCK + threadIdx.x;
    #pragma unroll 4
    for (int k = 0; k < ITERS; ++k, g += STRIDE4) {
        const vfloat4 s  = syn4[g];
        const vfloat4 xv = x4[g & 2047];   // 32 KB, L1-resident
        float a = 0.0f;
        a += ((s.x > 50.0f) && (xv.x != 0.0f)) ? 1.0f : 0.0f;
        a += ((s.y > 50.0f) && (xv.y != 0.0f)) ? 1.0f : 0.0f;
        a += ((s.z > 50.0f) && (xv.z != 0.0f)) ? 1.0f : 0.0f;
        a += ((s.w > 50.0f) && (xv.w != 0.0f)) ? 1.0f : 0.0f;
        #pragma unroll
        for (int off = 32; off > 0; off >>= 1) {
            a += __shfl_down(a, off, 64);
        }
        if (lane == 0) partial[g >> 6] = a;   // chunk id; row = chunk>>5
    }
}

// ---- Kernel A2: reduce partials + LIF scalars ----------------------------
__global__ __launch_bounds__(BLOCK) void snn_lif(
    const float* __restrict__ partial,  // [262144]
    const float* __restrict__ mem,
    const float* __restrict__ thr,
    const float* __restrict__ refr,
    float* __restrict__ out_spikes,
    float* __restrict__ out_mem,
    float* __restrict__ out_refr)
{
    const int row = blockIdx.x * BLOCK + threadIdx.x;   // 32 blocks
    const vfloat4* __restrict__ p4 =
        (const vfloat4*)(partial + (size_t)row * 32);
    float c = 0.0f;
    #pragma unroll
    for (int j = 0; j < 8; ++j) {
        const vfloat4 p = p4[j];
        c += p.x + p.y + p.z + p.w;     // exact: integer-valued floats
    }
    const float r = refr[row];
    const float v = mem[row] * 0.5f + c * (1.0f - r * 0.5f);
    const float spike = (v >= thr[row]) ? 1.0f : 0.0f;
    out_spikes[row] = spike;
    out_mem[row]    = v * (1.0f - spike);
    out_refr[row]   = fminf(fmaxf(r + spike - 0.1f, 0.0f), 1.0f);
}

// ---- Kernel B: flat trace stream -----------------------------------------
__global__ __launch_bounds__(BLOCK) void snn_trace_flat(
    const vfloat4* __restrict__ tr4,    // [TOTAL4]
    const vfloat4* __restrict__ x4,     // [2048]
    const float* __restrict__ spikes,   // [OUT_F]
    vfloat4* __restrict__ otr4)         // [TOTAL4]
{
    size_t g = (size_t)blockIdx.x * BLOCK + threadIdx.x;
    #pragma unroll 4
    for (int k = 0; k < ITERS; ++k, g += STRIDE4) {
        const float sp   = spikes[g >> 11];   // wave-uniform, L1-hit
        const vfloat4 t  = tr4[g];
        const vfloat4 xv = x4[g & 2047];      // L1-resident
        vfloat4 o;
        o.x = fminf(fmaxf(t.x * 0.8f + sp * xv.x, 0.0f), 5.0f);
        o.y = fminf(fmaxf(t.y * 0.8f + sp * xv.y, 0.0f), 5.0f);
        o.z = fminf(fmaxf(t.z * 0.8f + sp * xv.z, 0.0f), 5.0f);
        o.w = fminf(fmaxf(t.w * 0.8f + sp * xv.w, 0.0f), 5.0f);
        otr4[g] = o;
    }
}

extern "C" void kernel_launch(void* const* d_in, const int* in_sizes, int n_in,
                              void* d_out, int out_size, void* d_ws, size_t ws_size,
                              hipStream_t stream) {
    const float* x_in  = (const float*)d_in[0];  // spike_input
    const float* syn   = (const float*)d_in[1];  // synapse_states
    const float* mem   = (const float*)d_in[2];  // membrane_potential
    const float* thr   = (const float*)d_in[3];  // adaptive_threshold
    const float* trace = (const float*)d_in[4];  // eligibility_trace
    const float* refr  = (const float*)d_in[5];  // refractory_period

    float* out = (float*)d_out;
    float* out_spikes = out;                                     // [8192]
    float* out_mem    = out + OUT_F;                             // [8192]
    float* out_trace  = out + 2 * OUT_F;                         // [8192^2]
    float* out_refr   = out + 2 * OUT_F + (size_t)OUT_F * IN_F;  // [8192]

    float* partial = (float*)d_ws;   // 262144 floats = 1 MB scratch

    snn_dot_flat<<<GRID, BLOCK, 0, stream>>>(
        (const vfloat4*)syn, (const vfloat4*)x_in, partial);

    snn_lif<<<OUT_F / BLOCK, BLOCK, 0, stream>>>(
        partial, mem, thr, refr, out_spikes, out_mem, out_refr);

    snn_trace_flat<<<GRID, BLOCK, 0, stream>>>(
        (const vfloat4*)trace, (const vfloat4*)x_in, out_spikes,
        (vfloat4*)out_trace);
}